// Round 6
// baseline (104237.170 us; speedup 1.0000x reference)
//
#include <hip/hip_runtime.h>
#include <stdint.h>

#define N 4096
#define D 1024
#define TILE 512           // rows per sim/scan tile (8 tiles per round)
#define THRF 0.25f
#define NEGF (-3.0e38f)

// ---- All scratch lives in d_in[0] (16 MB, freed once E is copied to d_out).
// d_ws is never touched (R4 decoded impossible state transitions when using it).
// Layout: simT 8 MB | partner 16 KB | mcnt/acnt | mg/alive/consumed ~12 KB.

__global__ void k_init(uint8_t* alive, int* mcnt, int* acnt) {
    int x = blockIdx.x * blockDim.x + threadIdx.x;
    if (x < N) alive[x] = 1;
    if (x < 8) { mcnt[x] = 0; acnt[x] = (x == 0) ? N : 0; }
}

__global__ void k_mgzero(uint8_t* mg) {
    int x = blockIdx.x * blockDim.x + threadIdx.x;
    if (x < N) mg[x] = 0;
}

// sim tile: for rows i in [t0, t0+TILE), ALL j in [0,N):
// simT[r][j] = (float)( fp64_dot(E_i, E_j) / 1024 ).
// One thread per (i, j): fully sequential fp64 FMA over d — deterministic.
__global__ __launch_bounds__(64) void k_sim(const float* __restrict__ E,
                                            float* __restrict__ simT, int t0) {
    int i = t0 + blockIdx.y;
    int j = blockIdx.x * 64 + threadIdx.x;
    const float* ri = E + (size_t)i * D;
    const float* rj = E + (size_t)j * D;
    double a = 0.0;
    for (int d = 0; d < D; ++d)
        a = fma((double)ri[d], (double)rj[d], a);
    simT[(size_t)blockIdx.y * N + j] = (float)(a * (1.0 / 1024.0));
}

// LITERAL transcription of the reference scan body for rows [t0, t0+TILE):
//   cand = (j > i) & alive[j] & alive[i] & ~merged[j]
//   j* = argmax(where(cand, sim_row, NEG))   [first occurrence on ties]
//   do = ~merged[i] & (scores[j*] >= 0.25)
//   merged[j*] |= do ; partner[i] = do ? j* : -1
// One block; merged persisted in mg[] (global) across the 8 tile launches.
__global__ __launch_bounds__(256) void k_scan(const float* __restrict__ simT,
                                              const uint8_t* __restrict__ aliveG,
                                              uint8_t* __restrict__ mgG,
                                              int* __restrict__ partner, int t0,
                                              int* __restrict__ mcnt, int round) {
    __shared__ uint8_t mg[N];
    __shared__ uint8_t alv[N];
    __shared__ float rv[256];
    __shared__ int rj[256];
    int t = threadIdx.x;
    for (int x = t; x < N; x += 256) { mg[x] = mgG[x]; alv[x] = aliveG[x]; }
    __syncthreads();
    for (int r = 0; r < TILE; ++r) {
        int i = t0 + r;
        const float* row = simT + (size_t)r * N;
        float bv = NEGF;
        int bj = 0x7fffffff;
        for (int j = t; j < N; j += 256) {
            if (j > i && alv[j] && !mg[j]) {
                float v = row[j];
                if (v > bv) { bv = v; bj = j; }   // strict > keeps lowest j
            }
        }
        rv[t] = bv; rj[t] = bj;
        __syncthreads();
        for (int s = 128; s > 0; s >>= 1) {
            if (t < s) {
                float ov = rv[t + s]; int oj = rj[t + s];
                if (ov > rv[t] || (ov == rv[t] && oj < rj[t])) { rv[t] = ov; rj[t] = oj; }
            }
            __syncthreads();
        }
        if (t == 0) {
            // scores are NEG when !alive[i]; do also requires !merged[i]
            bool doit = alv[i] && !mg[i] && (rj[0] != 0x7fffffff) && (rv[0] >= THRF);
            if (doit) { partner[i] = rj[0]; mg[rj[0]] = 1; atomicAdd(&mcnt[round], 1); }
            else partner[i] = -1;
        }
        __syncthreads();
    }
    for (int x = t; x < N; x += 256) mgG[x] = mg[x];
}

__global__ void k_apply(const uint8_t* __restrict__ mg, uint8_t* __restrict__ alive,
                        uint8_t* __restrict__ consumed) {
    int x = blockIdx.x * blockDim.x + threadIdx.x;
    if (x < N) {
        uint8_t m = mg[x];
        consumed[x] = m;
        alive[x] = (uint8_t)(alive[x] && !m);
    }
}

// independent alive recount (audit input)
__global__ __launch_bounds__(256) void k_count(const uint8_t* __restrict__ alive,
                                               int* __restrict__ acnt, int slot) {
    int x = blockIdx.x * 256 + threadIdx.x;
    int lane = threadIdx.x & 63;
    unsigned long long b = __ballot(alive[x] != 0);
    if (lane == 0) atomicAdd(&acnt[slot], (int)__popcll(b));
}

__global__ void k_fuse(float* __restrict__ E, const int* __restrict__ partner) {
    int i = blockIdx.x;
    int p = partner[i];
    if (p < 0) return;
    float* ri = E + (size_t)i * D;
    const float* rp = E + (size_t)p * D;   // p is consumed, never itself fused
    for (int e = threadIdx.x; e < D; e += blockDim.x)
        ri[e] = fminf(ri[e] + rp[e], 1.0f);
}

__global__ void k_zero(float* __restrict__ E, const uint8_t* __restrict__ consumed) {
    int i = blockIdx.x;
    if (!consumed[i]) return;
    float* ri = E + (size_t)i * D;
    for (int e = threadIdx.x; e < D; e += blockDim.x) ri[e] = 0.0f;
}

__global__ void k_alive_out(const uint8_t* __restrict__ alive, float* __restrict__ outA) {
    int x = blockIdx.x * blockDim.x + threadIdx.x;
    if (x < N) outA[x] = alive[x] ? 1.0f : 0.0f;
}

// AUDIT: fires ONLY on invariant violation (after+m==before, 2m<=before).
__global__ void k_diag(const int* __restrict__ mcnt, const int* __restrict__ acnt,
                       float* __restrict__ out) {
    bool bad = false;
    for (int r = 0; r < 4; ++r) {
        int before = acnt[r], after = acnt[r + 1], m = mcnt[r];
        if (after + m != before) bad = true;
        if (2 * m > before) bad = true;
        if (m < 0 || m > 2048) bad = true;
    }
    if (bad) out[0] = (float)(8.0e6 + (double)mcnt[0] * 2048.0 + (double)mcnt[1]);
}

extern "C" void kernel_launch(void* const* d_in, const int* in_sizes, int n_in,
                              void* d_out, int out_size, void* d_ws, size_t ws_size,
                              hipStream_t stream) {
    const float* Ein = (const float*)d_in[0];
    float* E = (float*)d_out;                    // 4096*1024 fp32, updated in place
    float* outAlive = E + (size_t)N * D;         // 4096 floats (0/1)

    // arena = d_in[0] after the on-stream copy below (16 MB guaranteed)
    char* ws = (char*)d_in[0];
    float* simT = (float*)ws;      ws += (size_t)TILE * N * 4;   // 8 MB
    int* partner = (int*)ws;       ws += (size_t)N * 4;          // 16 KB
    int* mcnt = (int*)ws;          ws += 8 * 4;
    int* acnt = (int*)ws;          ws += 8 * 4;
    uint8_t* mg = (uint8_t*)ws;    ws += N;
    uint8_t* alive = (uint8_t*)ws; ws += N;
    uint8_t* consumed = (uint8_t*)ws;            // total ~8.4 MB << 16 MB

    hipMemcpyAsync(E, Ein, (size_t)N * D * sizeof(float), hipMemcpyDeviceToDevice, stream);
    k_init<<<(N + 255) / 256, 256, 0, stream>>>(alive, mcnt, acnt);

    for (int round = 0; round < 4; ++round) {
        k_mgzero<<<(N + 255) / 256, 256, 0, stream>>>(mg);
        for (int tile = 0; tile < N / TILE; ++tile) {
            int t0 = tile * TILE;
            k_sim<<<dim3(N / 64, TILE), 64, 0, stream>>>(E, simT, t0);
            k_scan<<<1, 256, 0, stream>>>(simT, alive, mg, partner, t0, mcnt, round);
        }
        k_apply<<<(N + 255) / 256, 256, 0, stream>>>(mg, alive, consumed);
        k_count<<<16, 256, 0, stream>>>(alive, acnt, round + 1);
        k_fuse<<<N, 256, 0, stream>>>(E, partner);
        k_zero<<<N, 256, 0, stream>>>(E, consumed);
    }
    k_alive_out<<<(N + 255) / 256, 256, 0, stream>>>(alive, outAlive);
    k_diag<<<1, 1, 0, stream>>>(mcnt, acnt, E);   // conditional sentinel only
}

// Round 7
// 54186.243 us; speedup vs baseline: 1.9237x; 1.9237x over previous
//
#include <hip/hip_runtime.h>
#include <stdint.h>

#define N 4096
#define D 1024
#define TILE 512           // rows per tile (8 tiles per round)
#define TOPK 16
#define THRF 0.25f
#define NEGF (-3.0e38f)
#define GBK 16

// ---- All scratch lives in d_in[0] (16 MB; harness restores it before every
// timed launch; we copy E to d_out first on-stream). d_ws is never used.
// Key numerics invariant (R6-proven): sims = fp32( fp64_fma_chain(d=0..1023) / 1024 ),
// ALL comparisons (argmax, ties, threshold) in fp32 — matches np decisions exactly.

__global__ void k_init(uint8_t* alive, int* mcnt, int* acnt) {
    int x = blockIdx.x * blockDim.x + threadIdx.x;
    if (x < N) alive[x] = 1;
    if (x < 8) { mcnt[x] = 0; acnt[x] = (x == 0) ? N : 0; }
}

__global__ void k_mgzero(uint8_t* mg) {
    int x = blockIdx.x * blockDim.x + threadIdx.x;
    if (x < N) mg[x] = 0;
}

// fp64 LDS-tiled GEMM -> fp32 sim tile. Rows i in [t0,t0+512), cols j in [bx0*64, 4096).
// Accumulation order per (i,j): d = 0..1023 ascending, single fp64 acc, fma each
// step — bit-identical to the R6-validated k_sim.
__global__ __launch_bounds__(256) void k_gemm(const float* __restrict__ E,
                                              float* __restrict__ simT,
                                              int t0, int bx0) {
    int bi = blockIdx.y;            // row block within tile: 0..7
    int bj = blockIdx.x + bx0;      // column block: bx0..63
    __shared__ float As[64][GBK + 1];
    __shared__ float Bs[64][GBK + 1];
    int t = threadIdx.x;
    int tr = t >> 4, tc = t & 15;
    double acc[4][4] = {};
    const float* Arow = E + ((size_t)t0 + (size_t)bi * 64) * D;
    const float* Brow = E + (size_t)bj * 64 * D;
    for (int k0 = 0; k0 < D; k0 += GBK) {
        for (int q = 0; q < 4; ++q) {
            int lin = t + 256 * q;           // 0..1023
            int r = lin >> 4, c = lin & 15;
            As[r][c] = Arow[(size_t)r * D + k0 + c];
            Bs[r][c] = Brow[(size_t)r * D + k0 + c];
        }
        __syncthreads();
        for (int kk = 0; kk < GBK; ++kk) {
            double a[4], b[4];
            for (int u = 0; u < 4; ++u) a[u] = (double)As[tr * 4 + u][kk];
            for (int v = 0; v < 4; ++v) b[v] = (double)Bs[tc * 4 + v][kk];
            for (int u = 0; u < 4; ++u)
                for (int v = 0; v < 4; ++v) acc[u][v] = fma(a[u], b[v], acc[u][v]);
        }
        __syncthreads();
    }
    int rbase = bi * 64 + tr * 4;
    int jbase = bj * 64 + tc * 4;
    for (int u = 0; u < 4; ++u)
        for (int v = 0; v < 4; ++v)
            simT[(size_t)(rbase + u) * N + (jbase + v)] =
                (float)(acc[u][v] * (1.0 / 1024.0));
}

// per-row top-16 in (val desc, idx asc) order over j > i, fp32 comparisons.
// No aliveness mask: dead rows are zeroed -> sim exactly 0.0f, below every live
// sim (>0) and below thr -> provably same decisions as the reference's NEG mask.
__global__ __launch_bounds__(256) void k_topk(const float* __restrict__ simT, int t0,
                                              float* __restrict__ tkv,
                                              int* __restrict__ tki,
                                              int* __restrict__ tkc) {
    int r = blockIdx.x;
    int i = t0 + r;
    int t = threadIdx.x;
    __shared__ float sv[N];
    __shared__ float pv[256];
    __shared__ int pj[256];
    const float* row = simT + (size_t)r * N;
    for (int j = t; j < N; j += 256) {
        float v = NEGF;
        if (j > i) v = row[j];
        sv[j] = v;
    }
    __syncthreads();
    int cnt = 0;
    for (int k = 0; k < TOPK; ++k) {
        float bv = NEGF;
        int bj = 0x7fffffff;
        for (int j = t; j < N; j += 256) {
            float v = sv[j];
            if (v > bv) { bv = v; bj = j; }      // strict > keeps lowest j
        }
        pv[t] = bv; pj[t] = bj;
        __syncthreads();
        for (int s = 128; s > 0; s >>= 1) {
            if (t < s) {
                float ov = pv[t + s]; int oj = pj[t + s];
                if (ov > pv[t] || (ov == pv[t] && oj < pj[t])) { pv[t] = ov; pj[t] = oj; }
            }
            __syncthreads();
        }
        if (pv[0] <= NEGF * 0.5f) break;         // uniform: no candidates left
        if (t == 0) {
            tkv[r * TOPK + k] = pv[0];
            tki[r * TOPK + k] = pj[0];
            sv[pj[0]] = NEGF;
        }
        cnt = k + 1;
        __syncthreads();
    }
    if (t == 0) tkc[r] = cnt;
}

// Sequential greedy matcher for one tile: single wave. Fast path: first
// unconsumed entry of the (val desc, idx asc) top-16 IS the reference argmax
// (proof: any j outside the list is ordered after entry 16). Fallback (all 16
// consumed & 16th >= thr & candidates exist beyond the list): full-row rescan
// of the materialized simT row.
__global__ __launch_bounds__(64) void k_match(const float* __restrict__ simT,
                                              const float* __restrict__ tkv,
                                              const int* __restrict__ tki,
                                              const int* __restrict__ tkc,
                                              uint8_t* __restrict__ mgG,
                                              int* __restrict__ partner, int t0,
                                              int* __restrict__ mcnt, int round) {
    __shared__ uint8_t mg_[N];
    __shared__ float ctv[TILE * TOPK];
    __shared__ int cti[TILE * TOPK];
    __shared__ int ccnt[TILE];
    volatile uint8_t* mg = mg_;
    int lane = threadIdx.x;
    for (int x = lane; x < N; x += 64) mg_[x] = mgG[x];
    for (int x = lane; x < TILE * TOPK; x += 64) { ctv[x] = tkv[x]; cti[x] = tki[x]; }
    for (int x = lane; x < TILE; x += 64) ccnt[x] = tkc[x];
    for (int r = 0; r < TILE; ++r) {
        int i = t0 + r;
        int cnt = ccnt[r];
        if (mg[i] || cnt == 0) {
            if (lane == 0) partner[i] = -1;
            continue;
        }
        float v = NEGF;
        int j = -1;
        bool ok = false;
        if (lane < cnt) {
            j = cti[r * TOPK + lane];
            v = ctv[r * TOPK + lane];
            ok = (mg[j] == 0);
        }
        unsigned long long m = __ballot(ok);
        if (m != 0ULL) {
            int f = __ffsll(m) - 1;
            float pvv = __shfl(v, f);
            int pjj = __shfl(j, f);
            if (pvv >= THRF) {
                if (lane == 0) { partner[i] = pjj; mg_[pjj] = 1; atomicAdd(&mcnt[round], 1); }
            } else if (lane == 0) {
                partner[i] = -1;
            }
        } else {
            bool fb = (cnt == TOPK) && (ctv[r * TOPK + TOPK - 1] >= THRF) &&
                      (N - 1 - i > TOPK);
            if (fb) {
                const float* row = simT + (size_t)r * N;
                float bv = NEGF;
                int bj = 0x7fffffff;
                for (int jj = i + 1 + lane; jj < N; jj += 64) {
                    if (!mg[jj]) {
                        float vv = row[jj];
                        if (vv > bv) { bv = vv; bj = jj; }
                    }
                }
                for (int off = 32; off > 0; off >>= 1) {
                    float ov = __shfl_down(bv, off);
                    int oj = __shfl_down(bj, off);
                    if (ov > bv || (ov == bv && oj < bj)) { bv = ov; bj = oj; }
                }
                if (lane == 0) {
                    if (bj != 0x7fffffff && bv >= THRF) {
                        partner[i] = bj; mg_[bj] = 1; atomicAdd(&mcnt[round], 1);
                    } else {
                        partner[i] = -1;
                    }
                }
            } else if (lane == 0) {
                partner[i] = -1;
            }
        }
    }
    for (int x = lane; x < N; x += 64) mgG[x] = mg_[x];
}

__global__ void k_apply(const uint8_t* __restrict__ mg, uint8_t* __restrict__ alive,
                        uint8_t* __restrict__ consumed) {
    int x = blockIdx.x * blockDim.x + threadIdx.x;
    if (x < N) {
        uint8_t m = mg[x];
        consumed[x] = m;
        alive[x] = (uint8_t)(alive[x] && !m);
    }
}

__global__ __launch_bounds__(256) void k_count(const uint8_t* __restrict__ alive,
                                               int* __restrict__ acnt, int slot) {
    int x = blockIdx.x * 256 + threadIdx.x;
    int lane = threadIdx.x & 63;
    unsigned long long b = __ballot(alive[x] != 0);
    if (lane == 0) atomicAdd(&acnt[slot], (int)__popcll(b));
}

__global__ void k_fuse(float* __restrict__ E, const int* __restrict__ partner) {
    int i = blockIdx.x;
    int p = partner[i];
    if (p < 0) return;
    float* ri = E + (size_t)i * D;
    const float* rp = E + (size_t)p * D;
    for (int e = threadIdx.x; e < D; e += blockDim.x)
        ri[e] = fminf(ri[e] + rp[e], 1.0f);
}

__global__ void k_zero(float* __restrict__ E, const uint8_t* __restrict__ consumed) {
    int i = blockIdx.x;
    if (!consumed[i]) return;
    float* ri = E + (size_t)i * D;
    for (int e = threadIdx.x; e < D; e += blockDim.x) ri[e] = 0.0f;
}

__global__ void k_alive_out(const uint8_t* __restrict__ alive, float* __restrict__ outA) {
    int x = blockIdx.x * blockDim.x + threadIdx.x;
    if (x < N) outA[x] = alive[x] ? 1.0f : 0.0f;
}

// AUDIT: fires ONLY on invariant violation (after+m==before, 2m<=before).
__global__ void k_diag(const int* __restrict__ mcnt, const int* __restrict__ acnt,
                       float* __restrict__ out) {
    bool bad = false;
    for (int r = 0; r < 4; ++r) {
        int before = acnt[r], after = acnt[r + 1], m = mcnt[r];
        if (after + m != before) bad = true;
        if (2 * m > before) bad = true;
        if (m < 0 || m > 2048) bad = true;
    }
    if (bad) out[0] = (float)(8.0e6 + (double)mcnt[0] * 2048.0 + (double)mcnt[1]);
}

extern "C" void kernel_launch(void* const* d_in, const int* in_sizes, int n_in,
                              void* d_out, int out_size, void* d_ws, size_t ws_size,
                              hipStream_t stream) {
    const float* Ein = (const float*)d_in[0];
    float* E = (float*)d_out;                    // 4096*1024 fp32, updated in place
    float* outAlive = E + (size_t)N * D;         // 4096 floats (0/1)

    // arena = d_in[0] after the on-stream copy below (16 MB guaranteed)
    char* ws = (char*)d_in[0];
    float* simT = (float*)ws;      ws += (size_t)TILE * N * 4;     // 8 MB
    float* tkv = (float*)ws;       ws += (size_t)TILE * TOPK * 4;  // 32 KB
    int* tki = (int*)ws;           ws += (size_t)TILE * TOPK * 4;  // 32 KB
    int* tkc = (int*)ws;           ws += (size_t)TILE * 4;         // 2 KB
    int* partner = (int*)ws;       ws += (size_t)N * 4;            // 16 KB
    int* mcnt = (int*)ws;          ws += 8 * 4;
    int* acnt = (int*)ws;          ws += 8 * 4;
    uint8_t* mg = (uint8_t*)ws;    ws += N;
    uint8_t* alive = (uint8_t*)ws; ws += N;
    uint8_t* consumed = (uint8_t*)ws;            // total ~8.1 MB << 16 MB

    hipMemcpyAsync(E, Ein, (size_t)N * D * sizeof(float), hipMemcpyDeviceToDevice, stream);
    k_init<<<(N + 255) / 256, 256, 0, stream>>>(alive, mcnt, acnt);

    for (int round = 0; round < 4; ++round) {
        k_mgzero<<<(N + 255) / 256, 256, 0, stream>>>(mg);
        for (int tile = 0; tile < N / TILE; ++tile) {
            int t0 = tile * TILE;
            int bx0 = t0 / 64;                    // skip never-read columns j < t0
            k_gemm<<<dim3(64 - bx0, TILE / 64), 256, 0, stream>>>(E, simT, t0, bx0);
            k_topk<<<TILE, 256, 0, stream>>>(simT, t0, tkv, tki, tkc);
            k_match<<<1, 64, 0, stream>>>(simT, tkv, tki, tkc, mg, partner, t0, mcnt, round);
        }
        k_apply<<<(N + 255) / 256, 256, 0, stream>>>(mg, alive, consumed);
        k_count<<<16, 256, 0, stream>>>(alive, acnt, round + 1);
        k_fuse<<<N, 256, 0, stream>>>(E, partner);
        k_zero<<<N, 256, 0, stream>>>(E, consumed);
    }
    k_alive_out<<<(N + 255) / 256, 256, 0, stream>>>(alive, outAlive);
    k_diag<<<1, 1, 0, stream>>>(mcnt, acnt, E);   // conditional sentinel only
}

// Round 8
// 26187.103 us; speedup vs baseline: 3.9805x; 2.0692x over previous
//
#include <hip/hip_runtime.h>
#include <stdint.h>

#define N 4096
#define D 1024
#define TILE 512           // rows per tile (8 tiles per round)
#define TOPK 16
#define THRF 0.25f
#define NEGF (-3.0e38f)
#define GBK 16

// ---- All scratch lives in d_in[0] (16 MB; harness restores it before every
// timed launch; we copy E to d_out first on-stream). d_ws is never used.
// Numerics invariant (R6/R7-proven): sims = fp32( fp64_fma_chain(d=0..1023) / 1024 ),
// ALL comparisons (argmax, ties, threshold) in fp32 — matches np decisions exactly.

__global__ void k_init(uint8_t* alive, int* mcnt, int* acnt) {
    int x = blockIdx.x * blockDim.x + threadIdx.x;
    if (x < N) alive[x] = 1;
    if (x < 8) { mcnt[x] = 0; acnt[x] = (x == 0) ? N : 0; }
}

__global__ void k_mgzero(unsigned long long* mgW) {
    int x = threadIdx.x;
    if (x < 64) mgW[x] = 0ull;
}

// fp64 LDS-tiled GEMM -> fp32 sim tile. Rows i in [t0,t0+512), cols j in [bx0*64, 4096).
// Accumulation order per (i,j): d = 0..1023 ascending, single fp64 acc, fma each
// step — bit-identical to the R6-validated k_sim.
__global__ __launch_bounds__(256) void k_gemm(const float* __restrict__ E,
                                              float* __restrict__ simT,
                                              int t0, int bx0) {
    int bi = blockIdx.y;            // row block within tile: 0..7
    int bj = blockIdx.x + bx0;      // column block: bx0..63
    __shared__ float As[64][GBK + 1];
    __shared__ float Bs[64][GBK + 1];
    int t = threadIdx.x;
    int tr = t >> 4, tc = t & 15;
    double acc[4][4] = {};
    const float* Arow = E + ((size_t)t0 + (size_t)bi * 64) * D;
    const float* Brow = E + (size_t)bj * 64 * D;
    for (int k0 = 0; k0 < D; k0 += GBK) {
        for (int q = 0; q < 4; ++q) {
            int lin = t + 256 * q;           // 0..1023
            int r = lin >> 4, c = lin & 15;
            As[r][c] = Arow[(size_t)r * D + k0 + c];
            Bs[r][c] = Brow[(size_t)r * D + k0 + c];
        }
        __syncthreads();
        for (int kk = 0; kk < GBK; ++kk) {
            double a[4], b[4];
            for (int u = 0; u < 4; ++u) a[u] = (double)As[tr * 4 + u][kk];
            for (int v = 0; v < 4; ++v) b[v] = (double)Bs[tc * 4 + v][kk];
            for (int u = 0; u < 4; ++u)
                for (int v = 0; v < 4; ++v) acc[u][v] = fma(a[u], b[v], acc[u][v]);
        }
        __syncthreads();
    }
    int rbase = bi * 64 + tr * 4;
    int jbase = bj * 64 + tc * 4;
    for (int u = 0; u < 4; ++u)
        for (int v = 0; v < 4; ++v)
            simT[(size_t)(rbase + u) * N + (jbase + v)] =
                (float)(acc[u][v] * (1.0 / 1024.0));
}

// per-row top-16 in (val desc, idx asc) order over j > i, fp32 comparisons.
__global__ __launch_bounds__(256) void k_topk(const float* __restrict__ simT, int t0,
                                              float* __restrict__ tkv,
                                              int* __restrict__ tki,
                                              int* __restrict__ tkc) {
    int r = blockIdx.x;
    int i = t0 + r;
    int t = threadIdx.x;
    __shared__ float sv[N];
    __shared__ float pv[256];
    __shared__ int pj[256];
    const float* row = simT + (size_t)r * N;
    for (int j = t; j < N; j += 256) {
        float v = NEGF;
        if (j > i) v = row[j];
        sv[j] = v;
    }
    __syncthreads();
    int cnt = 0;
    for (int k = 0; k < TOPK; ++k) {
        float bv = NEGF;
        int bj = 0x7fffffff;
        for (int j = t; j < N; j += 256) {
            float v = sv[j];
            if (v > bv) { bv = v; bj = j; }      // strict > keeps lowest j
        }
        pv[t] = bv; pj[t] = bj;
        __syncthreads();
        for (int s = 128; s > 0; s >>= 1) {
            if (t < s) {
                float ov = pv[t + s]; int oj = pj[t + s];
                if (ov > pv[t] || (ov == pv[t] && oj < pj[t])) { pv[t] = ov; pj[t] = oj; }
            }
            __syncthreads();
        }
        if (pv[0] <= NEGF * 0.5f) break;         // uniform: no candidates left
        if (t == 0) {
            tkv[r * TOPK + k] = pv[0];
            tki[r * TOPK + k] = pj[0];
            sv[pj[0]] = NEGF;
        }
        cnt = k + 1;
        __syncthreads();
    }
    if (t == 0) tkc[r] = cnt;
}

// Sequential greedy matcher, single wave. mg bitset lives in REGISTERS:
// lane L owns bits for columns [64L, 64L+64). Tests via __shfl, sets by the
// owning lane — zero memory traffic in the row loop. Fallback (all top-16
// consumed & 16th >= thr): pipelined float4 scan of the materialized simT row.
__global__ __launch_bounds__(64) void k_match(const float* __restrict__ simT,
                                              const float* __restrict__ tkv,
                                              const int* __restrict__ tki,
                                              const int* __restrict__ tkc,
                                              unsigned long long* __restrict__ mgW,
                                              int* __restrict__ partner, int t0,
                                              int* __restrict__ mcnt, int round) {
    __shared__ float ctv[TILE * TOPK];
    __shared__ int cti[TILE * TOPK];
    __shared__ int ccnt[TILE];
    int lane = threadIdx.x;
    for (int x = lane; x < TILE * TOPK; x += 64) { ctv[x] = tkv[x]; cti[x] = tki[x]; }
    for (int x = lane; x < TILE; x += 64) ccnt[x] = tkc[x];
    unsigned long long mw = mgW[lane];           // lane's 64-column mask word
    int nmerge = 0;
    __syncthreads();
    // software-pipelined candidate regs for row r
    int cnt_n = ccnt[0];
    float v_n = (lane < TOPK) ? ctv[lane] : NEGF;
    int j_n = (lane < TOPK) ? cti[lane] : -1;
    for (int r = 0; r < TILE; ++r) {
        int i = t0 + r;
        int cnt = cnt_n;
        float v = v_n;
        int j = j_n;
        if (r + 1 < TILE) {                      // prefetch next row's candidates
            cnt_n = ccnt[r + 1];
            if (lane < TOPK) {
                v_n = ctv[(r + 1) * TOPK + lane];
                j_n = cti[(r + 1) * TOPK + lane];
            }
        }
        unsigned long long iw = __shfl(mw, i >> 6);
        bool idead = (iw >> (i & 63)) & 1ull;
        if (idead || cnt == 0) {
            if (lane == 0) partner[i] = -1;
            continue;
        }
        unsigned long long jw = __shfl(mw, (j < 0 ? 0 : j) >> 6);
        bool ok = (lane < cnt) && !((jw >> (j & 63)) & 1ull);
        unsigned long long m = __ballot(ok);
        if (m != 0ull) {
            int f = __ffsll((long long)m) - 1;   // first in (val desc, idx asc) order
            float pvv = __shfl(v, f);
            int pjj = __shfl(j, f);
            if (pvv >= THRF) {
                if (lane == (pjj >> 6)) mw |= 1ull << (pjj & 63);
                if (lane == 0) { partner[i] = pjj; ++nmerge; }
            } else if (lane == 0) {
                partner[i] = -1;
            }
        } else {
            float vlast = __shfl(v, TOPK - 1);   // 16th list value, no LDS read
            bool fb = (cnt == TOPK) && (vlast >= THRF) && (N - 1 - i > TOPK);
            if (fb) {
                const float* row = simT + (size_t)r * N;
                float bv = NEGF;
                int bc = 0x7fffffff;
                int bbase = (lane & 15) * 4;
                for (int k = 0; k < N / 256; ++k) {
                    if (k * 256 + 255 <= i) continue;        // uniform skip
                    unsigned long long w = __shfl(mw, k * 4 + (lane >> 4));
                    const float4 f4 = *(const float4*)(row + k * 256 + 4 * lane);
                    int cb = k * 256 + 4 * lane;
                    {   float val = f4.x; int c = cb;
                        if (c > i && !((w >> (bbase + 0)) & 1ull) && val > bv) { bv = val; bc = c; } }
                    {   float val = f4.y; int c = cb + 1;
                        if (c > i && !((w >> (bbase + 1)) & 1ull) && val > bv) { bv = val; bc = c; } }
                    {   float val = f4.z; int c = cb + 2;
                        if (c > i && !((w >> (bbase + 2)) & 1ull) && val > bv) { bv = val; bc = c; } }
                    {   float val = f4.w; int c = cb + 3;
                        if (c > i && !((w >> (bbase + 3)) & 1ull) && val > bv) { bv = val; bc = c; } }
                }
                for (int off = 32; off > 0; off >>= 1) {     // (val desc, col asc)
                    float ov = __shfl_down(bv, off);
                    int oc = __shfl_down(bc, off);
                    if (ov > bv || (ov == bv && oc < bc)) { bv = ov; bc = oc; }
                }
                float bvf = __shfl(bv, 0);
                int bcf = __shfl(bc, 0);
                bool doit = (bcf != 0x7fffffff) && (bvf >= THRF);
                if (doit) {
                    if (lane == (bcf >> 6)) mw |= 1ull << (bcf & 63);
                    if (lane == 0) { partner[i] = bcf; ++nmerge; }
                } else if (lane == 0) {
                    partner[i] = -1;
                }
            } else if (lane == 0) {
                partner[i] = -1;
            }
        }
    }
    mgW[lane] = mw;
    if (lane == 0 && nmerge) atomicAdd(&mcnt[round], nmerge);
}

__global__ void k_apply(const unsigned long long* __restrict__ mgW,
                        uint8_t* __restrict__ alive, uint8_t* __restrict__ consumed) {
    int x = blockIdx.x * blockDim.x + threadIdx.x;
    if (x < N) {
        uint8_t m = (uint8_t)((mgW[x >> 6] >> (x & 63)) & 1ull);
        consumed[x] = m;
        alive[x] = (uint8_t)(alive[x] && !m);
    }
}

__global__ __launch_bounds__(256) void k_count(const uint8_t* __restrict__ alive,
                                               int* __restrict__ acnt, int slot) {
    int x = blockIdx.x * 256 + threadIdx.x;
    int lane = threadIdx.x & 63;
    unsigned long long b = __ballot(alive[x] != 0);
    if (lane == 0) atomicAdd(&acnt[slot], (int)__popcll(b));
}

__global__ void k_fuse(float* __restrict__ E, const int* __restrict__ partner) {
    int i = blockIdx.x;
    int p = partner[i];
    if (p < 0) return;
    float* ri = E + (size_t)i * D;
    const float* rp = E + (size_t)p * D;
    for (int e = threadIdx.x; e < D; e += blockDim.x)
        ri[e] = fminf(ri[e] + rp[e], 1.0f);
}

__global__ void k_zero(float* __restrict__ E, const uint8_t* __restrict__ consumed) {
    int i = blockIdx.x;
    if (!consumed[i]) return;
    float* ri = E + (size_t)i * D;
    for (int e = threadIdx.x; e < D; e += blockDim.x) ri[e] = 0.0f;
}

__global__ void k_alive_out(const uint8_t* __restrict__ alive, float* __restrict__ outA) {
    int x = blockIdx.x * blockDim.x + threadIdx.x;
    if (x < N) outA[x] = alive[x] ? 1.0f : 0.0f;
}

// AUDIT: fires ONLY on invariant violation (after+m==before, 2m<=before).
__global__ void k_diag(const int* __restrict__ mcnt, const int* __restrict__ acnt,
                       float* __restrict__ out) {
    bool bad = false;
    for (int r = 0; r < 4; ++r) {
        int before = acnt[r], after = acnt[r + 1], m = mcnt[r];
        if (after + m != before) bad = true;
        if (2 * m > before) bad = true;
        if (m < 0 || m > 2048) bad = true;
    }
    if (bad) out[0] = (float)(8.0e6 + (double)mcnt[0] * 2048.0 + (double)mcnt[1]);
}

extern "C" void kernel_launch(void* const* d_in, const int* in_sizes, int n_in,
                              void* d_out, int out_size, void* d_ws, size_t ws_size,
                              hipStream_t stream) {
    const float* Ein = (const float*)d_in[0];
    float* E = (float*)d_out;                    // 4096*1024 fp32, updated in place
    float* outAlive = E + (size_t)N * D;         // 4096 floats (0/1)

    // arena = d_in[0] after the on-stream copy below (16 MB guaranteed)
    char* ws = (char*)d_in[0];
    float* simT = (float*)ws;      ws += (size_t)TILE * N * 4;     // 8 MB
    float* tkv = (float*)ws;       ws += (size_t)TILE * TOPK * 4;  // 32 KB
    int* tki = (int*)ws;           ws += (size_t)TILE * TOPK * 4;  // 32 KB
    int* tkc = (int*)ws;           ws += (size_t)TILE * 4;         // 2 KB
    int* partner = (int*)ws;       ws += (size_t)N * 4;            // 16 KB
    int* mcnt = (int*)ws;          ws += 8 * 4;
    int* acnt = (int*)ws;          ws += 8 * 4;
    unsigned long long* mgW = (unsigned long long*)ws; ws += 64 * 8;
    uint8_t* alive = (uint8_t*)ws; ws += N;
    uint8_t* consumed = (uint8_t*)ws;            // total ~8.1 MB << 16 MB

    hipMemcpyAsync(E, Ein, (size_t)N * D * sizeof(float), hipMemcpyDeviceToDevice, stream);
    k_init<<<(N + 255) / 256, 256, 0, stream>>>(alive, mcnt, acnt);

    for (int round = 0; round < 4; ++round) {
        k_mgzero<<<1, 64, 0, stream>>>(mgW);
        for (int tile = 0; tile < N / TILE; ++tile) {
            int t0 = tile * TILE;
            int bx0 = t0 / 64;                    // skip never-read columns j < t0
            k_gemm<<<dim3(64 - bx0, TILE / 64), 256, 0, stream>>>(E, simT, t0, bx0);
            k_topk<<<TILE, 256, 0, stream>>>(simT, t0, tkv, tki, tkc);
            k_match<<<1, 64, 0, stream>>>(simT, tkv, tki, tkc, mgW, partner, t0, mcnt, round);
        }
        k_apply<<<(N + 255) / 256, 256, 0, stream>>>(mgW, alive, consumed);
        k_count<<<16, 256, 0, stream>>>(alive, acnt, round + 1);
        k_fuse<<<N, 256, 0, stream>>>(E, partner);
        k_zero<<<N, 256, 0, stream>>>(E, consumed);
    }
    k_alive_out<<<(N + 255) / 256, 256, 0, stream>>>(alive, outAlive);
    k_diag<<<1, 1, 0, stream>>>(mcnt, acnt, E);   // conditional sentinel only
}

// Round 9
// 17786.768 us; speedup vs baseline: 5.8604x; 1.4723x over previous
//
#include <hip/hip_runtime.h>
#include <stdint.h>

#define N 4096
#define D 1024
#define TILE 512           // rows per tile (8 tiles per round)
#define TOPK 16
#define THRF 0.25f
#define NEGF (-3.0e38f)
#define GBK 16

// ---- All scratch lives in d_in[0] (16 MB; harness restores it before every
// timed launch; we copy E to d_out first on-stream). d_ws is never used.
// Numerics invariant (R6/R7-proven): sims = fp32( fp64_fma_chain(d=0..1023) / 1024 ),
// ALL comparisons (argmax, ties, threshold) in fp32 — matches np decisions exactly.

__global__ void k_init(uint8_t* alive, int* mcnt, int* acnt) {
    int x = blockIdx.x * blockDim.x + threadIdx.x;
    if (x < N) alive[x] = 1;
    if (x < 8) { mcnt[x] = 0; acnt[x] = (x == 0) ? N : 0; }
}

__global__ void k_mgzero(unsigned long long* mgW) {
    int x = threadIdx.x;
    if (x < 64) mgW[x] = 0ull;
}

// fp64 LDS-tiled GEMM -> fp32 sim tile. Rows i in [t0,t0+512), cols j in [bx0*64, 4096).
__global__ __launch_bounds__(256) void k_gemm(const float* __restrict__ E,
                                              float* __restrict__ simT,
                                              int t0, int bx0) {
    int bi = blockIdx.y;            // row block within tile: 0..7
    int bj = blockIdx.x + bx0;      // column block: bx0..63
    __shared__ float As[64][GBK + 1];
    __shared__ float Bs[64][GBK + 1];
    int t = threadIdx.x;
    int tr = t >> 4, tc = t & 15;
    double acc[4][4] = {};
    const float* Arow = E + ((size_t)t0 + (size_t)bi * 64) * D;
    const float* Brow = E + (size_t)bj * 64 * D;
    for (int k0 = 0; k0 < D; k0 += GBK) {
        for (int q = 0; q < 4; ++q) {
            int lin = t + 256 * q;           // 0..1023
            int r = lin >> 4, c = lin & 15;
            As[r][c] = Arow[(size_t)r * D + k0 + c];
            Bs[r][c] = Brow[(size_t)r * D + k0 + c];
        }
        __syncthreads();
        for (int kk = 0; kk < GBK; ++kk) {
            double a[4], b[4];
            for (int u = 0; u < 4; ++u) a[u] = (double)As[tr * 4 + u][kk];
            for (int v = 0; v < 4; ++v) b[v] = (double)Bs[tc * 4 + v][kk];
            for (int u = 0; u < 4; ++u)
                for (int v = 0; v < 4; ++v) acc[u][v] = fma(a[u], b[v], acc[u][v]);
        }
        __syncthreads();
    }
    int rbase = bi * 64 + tr * 4;
    int jbase = bj * 64 + tc * 4;
    for (int u = 0; u < 4; ++u)
        for (int v = 0; v < 4; ++v)
            simT[(size_t)(rbase + u) * N + (jbase + v)] =
                (float)(acc[u][v] * (1.0 / 1024.0));
}

// per-row top-16 in (val desc, idx asc) order over j > i, fp32 comparisons.
__global__ __launch_bounds__(256) void k_topk(const float* __restrict__ simT, int t0,
                                              float* __restrict__ tkv,
                                              int* __restrict__ tki,
                                              int* __restrict__ tkc) {
    int r = blockIdx.x;
    int i = t0 + r;
    int t = threadIdx.x;
    __shared__ float sv[N];
    __shared__ float pv[256];
    __shared__ int pj[256];
    const float* row = simT + (size_t)r * N;
    for (int j = t; j < N; j += 256) {
        float v = NEGF;
        if (j > i) v = row[j];
        sv[j] = v;
    }
    __syncthreads();
    int cnt = 0;
    for (int k = 0; k < TOPK; ++k) {
        float bv = NEGF;
        int bj = 0x7fffffff;
        for (int j = t; j < N; j += 256) {
            float v = sv[j];
            if (v > bv) { bv = v; bj = j; }      // strict > keeps lowest j
        }
        pv[t] = bv; pj[t] = bj;
        __syncthreads();
        for (int s = 128; s > 0; s >>= 1) {
            if (t < s) {
                float ov = pv[t + s]; int oj = pj[t + s];
                if (ov > pv[t] || (ov == pv[t] && oj < pj[t])) { pv[t] = ov; pj[t] = oj; }
            }
            __syncthreads();
        }
        if (pv[0] <= NEGF * 0.5f) break;         // uniform: no candidates left
        if (t == 0) {
            tkv[r * TOPK + k] = pv[0];
            tki[r * TOPK + k] = pj[0];
            sv[pj[0]] = NEGF;
        }
        cnt = k + 1;
        __syncthreads();
    }
    if (t == 0) tkc[r] = cnt;
}

// Sequential greedy matcher, single wave. mg bitset in registers (lane L owns
// cols [64L,64L+64)). Fallback: ALL row blocks prefetched into registers first
// (one vmcnt drain ~1 latency instead of 16 serialized remote-L2 round trips),
// then tree-of-4 per block + 16-fold with (val desc, col asc) ordering.
__global__ __launch_bounds__(64) void k_match(const float* __restrict__ simT,
                                              const float* __restrict__ tkv,
                                              const int* __restrict__ tki,
                                              const int* __restrict__ tkc,
                                              unsigned long long* __restrict__ mgW,
                                              int* __restrict__ partner, int t0,
                                              int* __restrict__ mcnt, int round) {
    __shared__ float ctv[TILE * TOPK];
    __shared__ int cti[TILE * TOPK];
    __shared__ int ccnt[TILE];
    int lane = threadIdx.x;
    for (int x = lane; x < TILE * TOPK; x += 64) { ctv[x] = tkv[x]; cti[x] = tki[x]; }
    for (int x = lane; x < TILE; x += 64) ccnt[x] = tkc[x];
    unsigned long long mw = mgW[lane];           // lane's 64-column mask word
    int nmerge = 0;
    __syncthreads();
    int cnt_n = ccnt[0];
    float v_n = (lane < TOPK) ? ctv[lane] : NEGF;
    int j_n = (lane < TOPK) ? cti[lane] : -1;
    for (int r = 0; r < TILE; ++r) {
        int i = t0 + r;
        int cnt = cnt_n;
        float v = v_n;
        int j = j_n;
        if (r + 1 < TILE) {                      // prefetch next row's candidates
            cnt_n = ccnt[r + 1];
            if (lane < TOPK) {
                v_n = ctv[(r + 1) * TOPK + lane];
                j_n = cti[(r + 1) * TOPK + lane];
            }
        }
        unsigned long long iw = __shfl(mw, i >> 6);
        bool idead = (iw >> (i & 63)) & 1ull;
        if (idead || cnt == 0) {
            if (lane == 0) partner[i] = -1;
            continue;
        }
        unsigned long long jw = __shfl(mw, (j < 0 ? 0 : j) >> 6);
        bool ok = (lane < cnt) && !((jw >> (j & 63)) & 1ull);
        unsigned long long m = __ballot(ok);
        if (m != 0ull) {
            int f = __ffsll((long long)m) - 1;   // first in (val desc, idx asc) order
            float pvv = __shfl(v, f);
            int pjj = __shfl(j, f);
            if (pvv >= THRF) {
                if (lane == (pjj >> 6)) mw |= 1ull << (pjj & 63);
                if (lane == 0) { partner[i] = pjj; ++nmerge; }
            } else if (lane == 0) {
                partner[i] = -1;
            }
        } else {
            float vlast = __shfl(v, TOPK - 1);   // 16th list value, no LDS read
            bool fb = (cnt == TOPK) && (vlast >= THRF) && (N - 1 - i > TOPK);
            if (fb) {
                const float* row = simT + (size_t)r * N;
                int kfirst = i >> 8;             // uniform: first block with cols > i
                // 1) issue ALL needed loads back-to-back (independent)
                float4 f4[16];
                #pragma unroll
                for (int k = 0; k < 16; ++k)
                    if (k >= kfirst) f4[k] = *(const float4*)(row + k * 256 + 4 * lane);
                // 2) per-block tree-of-4, fold across blocks (ascending k:
                //    ties keep earlier=lower col automatically)
                int bbase = (lane & 15) * 4;
                float bv = NEGF;
                int bc = 0x7fffffff;
                #pragma unroll
                for (int k = 0; k < 16; ++k) {
                    if (k < kfirst) continue;
                    unsigned long long w = __shfl(mw, k * 4 + (lane >> 4));
                    int cb = k * 256 + 4 * lane;
                    float x0 = (cb + 0 > i && !((w >> (bbase + 0)) & 1ull)) ? f4[k].x : NEGF;
                    float x1 = (cb + 1 > i && !((w >> (bbase + 1)) & 1ull)) ? f4[k].y : NEGF;
                    float x2 = (cb + 2 > i && !((w >> (bbase + 2)) & 1ull)) ? f4[k].z : NEGF;
                    float x3 = (cb + 3 > i && !((w >> (bbase + 3)) & 1ull)) ? f4[k].w : NEGF;
                    float va = (x1 > x0) ? x1 : x0;  int ca = (x1 > x0) ? cb + 1 : cb;
                    float vb = (x3 > x2) ? x3 : x2;  int cd = (x3 > x2) ? cb + 3 : cb + 2;
                    float vk = (vb > va) ? vb : va;  int ck = (vb > va) ? cd : ca;
                    if (vk > bv) { bv = vk; bc = ck; }   // ties keep earlier block
                }
                // 3) cross-lane reduction, (val desc, col asc)
                for (int off = 32; off > 0; off >>= 1) {
                    float ov = __shfl_down(bv, off);
                    int oc = __shfl_down(bc, off);
                    if (ov > bv || (ov == bv && oc < bc)) { bv = ov; bc = oc; }
                }
                float bvf = __shfl(bv, 0);
                int bcf = __shfl(bc, 0);
                bool doit = (bcf != 0x7fffffff) && (bvf >= THRF);
                if (doit) {
                    if (lane == (bcf >> 6)) mw |= 1ull << (bcf & 63);
                    if (lane == 0) { partner[i] = bcf; ++nmerge; }
                } else if (lane == 0) {
                    partner[i] = -1;
                }
            } else if (lane == 0) {
                partner[i] = -1;
            }
        }
    }
    mgW[lane] = mw;
    if (lane == 0 && nmerge) atomicAdd(&mcnt[round], nmerge);
}

__global__ void k_apply(const unsigned long long* __restrict__ mgW,
                        uint8_t* __restrict__ alive, uint8_t* __restrict__ consumed) {
    int x = blockIdx.x * blockDim.x + threadIdx.x;
    if (x < N) {
        uint8_t m = (uint8_t)((mgW[x >> 6] >> (x & 63)) & 1ull);
        consumed[x] = m;
        alive[x] = (uint8_t)(alive[x] && !m);
    }
}

__global__ __launch_bounds__(256) void k_count(const uint8_t* __restrict__ alive,
                                               int* __restrict__ acnt, int slot) {
    int x = blockIdx.x * 256 + threadIdx.x;
    int lane = threadIdx.x & 63;
    unsigned long long b = __ballot(alive[x] != 0);
    if (lane == 0) atomicAdd(&acnt[slot], (int)__popcll(b));
}

__global__ void k_fuse(float* __restrict__ E, const int* __restrict__ partner) {
    int i = blockIdx.x;
    int p = partner[i];
    if (p < 0) return;
    float* ri = E + (size_t)i * D;
    const float* rp = E + (size_t)p * D;
    for (int e = threadIdx.x; e < D; e += blockDim.x)
        ri[e] = fminf(ri[e] + rp[e], 1.0f);
}

__global__ void k_zero(float* __restrict__ E, const uint8_t* __restrict__ consumed) {
    int i = blockIdx.x;
    if (!consumed[i]) return;
    float* ri = E + (size_t)i * D;
    for (int e = threadIdx.x; e < D; e += blockDim.x) ri[e] = 0.0f;
}

__global__ void k_alive_out(const uint8_t* __restrict__ alive, float* __restrict__ outA) {
    int x = blockIdx.x * blockDim.x + threadIdx.x;
    if (x < N) outA[x] = alive[x] ? 1.0f : 0.0f;
}

// AUDIT: fires ONLY on invariant violation (after+m==before, 2m<=before).
__global__ void k_diag(const int* __restrict__ mcnt, const int* __restrict__ acnt,
                       float* __restrict__ out) {
    bool bad = false;
    for (int r = 0; r < 4; ++r) {
        int before = acnt[r], after = acnt[r + 1], m = mcnt[r];
        if (after + m != before) bad = true;
        if (2 * m > before) bad = true;
        if (m < 0 || m > 2048) bad = true;
    }
    if (bad) out[0] = (float)(8.0e6 + (double)mcnt[0] * 2048.0 + (double)mcnt[1]);
}

extern "C" void kernel_launch(void* const* d_in, const int* in_sizes, int n_in,
                              void* d_out, int out_size, void* d_ws, size_t ws_size,
                              hipStream_t stream) {
    const float* Ein = (const float*)d_in[0];
    float* E = (float*)d_out;                    // 4096*1024 fp32, updated in place
    float* outAlive = E + (size_t)N * D;         // 4096 floats (0/1)

    // arena = d_in[0] after the on-stream copy below (16 MB guaranteed)
    char* ws = (char*)d_in[0];
    float* simT = (float*)ws;      ws += (size_t)TILE * N * 4;     // 8 MB
    float* tkv = (float*)ws;       ws += (size_t)TILE * TOPK * 4;  // 32 KB
    int* tki = (int*)ws;           ws += (size_t)TILE * TOPK * 4;  // 32 KB
    int* tkc = (int*)ws;           ws += (size_t)TILE * 4;         // 2 KB
    int* partner = (int*)ws;       ws += (size_t)N * 4;            // 16 KB
    int* mcnt = (int*)ws;          ws += 8 * 4;
    int* acnt = (int*)ws;          ws += 8 * 4;
    unsigned long long* mgW = (unsigned long long*)ws; ws += 64 * 8;
    uint8_t* alive = (uint8_t*)ws; ws += N;
    uint8_t* consumed = (uint8_t*)ws;            // total ~8.1 MB << 16 MB

    hipMemcpyAsync(E, Ein, (size_t)N * D * sizeof(float), hipMemcpyDeviceToDevice, stream);
    k_init<<<(N + 255) / 256, 256, 0, stream>>>(alive, mcnt, acnt);

    for (int round = 0; round < 4; ++round) {
        k_mgzero<<<1, 64, 0, stream>>>(mgW);
        for (int tile = 0; tile < N / TILE; ++tile) {
            int t0 = tile * TILE;
            int bx0 = t0 / 64;                    // skip never-read columns j < t0
            k_gemm<<<dim3(64 - bx0, TILE / 64), 256, 0, stream>>>(E, simT, t0, bx0);
            k_topk<<<TILE, 256, 0, stream>>>(simT, t0, tkv, tki, tkc);
            k_match<<<1, 64, 0, stream>>>(simT, tkv, tki, tkc, mgW, partner, t0, mcnt, round);
        }
        k_apply<<<(N + 255) / 256, 256, 0, stream>>>(mgW, alive, consumed);
        k_count<<<16, 256, 0, stream>>>(alive, acnt, round + 1);
        k_fuse<<<N, 256, 0, stream>>>(E, partner);
        k_zero<<<N, 256, 0, stream>>>(E, consumed);
    }
    k_alive_out<<<(N + 255) / 256, 256, 0, stream>>>(alive, outAlive);
    k_diag<<<1, 1, 0, stream>>>(mcnt, acnt, E);   // conditional sentinel only
}

// Round 10
// 17641.167 us; speedup vs baseline: 5.9087x; 1.0083x over previous
//
#include <hip/hip_runtime.h>
#include <stdint.h>

#define N 4096
#define D 1024
#define TILE 512           // rows per tile (8 tiles per round)
#define TOPK 16
#define THRF 0.25f
#define NEGF (-3.0e38f)
#define GBK 16

// ---- All scratch lives in d_in[0] (16 MB; harness restores it before every
// timed launch; we copy E to d_out first on-stream). d_ws is never used.
// Numerics invariant (R6/R7-proven): sims = fp32( fp64_fma_chain(d=0..1023) / 1024 ),
// ALL comparisons (argmax, ties, threshold) in fp32 — matches np decisions exactly.

__global__ void k_init(uint8_t* alive, int* mcnt, int* acnt) {
    int x = blockIdx.x * blockDim.x + threadIdx.x;
    if (x < N) alive[x] = 1;
    if (x < 8) { mcnt[x] = 0; acnt[x] = (x == 0) ? N : 0; }
}

__global__ void k_mgzero(unsigned long long* mgW) {
    int x = threadIdx.x;
    if (x < 64) mgW[x] = 0ull;
}

// fp64 LDS-tiled GEMM -> fp32 sim tile. Rows i in [t0,t0+512), cols j in [bx0*64, 4096).
__global__ __launch_bounds__(256) void k_gemm(const float* __restrict__ E,
                                              float* __restrict__ simT,
                                              int t0, int bx0) {
    int bi = blockIdx.y;            // row block within tile: 0..7
    int bj = blockIdx.x + bx0;      // column block: bx0..63
    __shared__ float As[64][GBK + 1];
    __shared__ float Bs[64][GBK + 1];
    int t = threadIdx.x;
    int tr = t >> 4, tc = t & 15;
    double acc[4][4] = {};
    const float* Arow = E + ((size_t)t0 + (size_t)bi * 64) * D;
    const float* Brow = E + (size_t)bj * 64 * D;
    for (int k0 = 0; k0 < D; k0 += GBK) {
        for (int q = 0; q < 4; ++q) {
            int lin = t + 256 * q;           // 0..1023
            int r = lin >> 4, c = lin & 15;
            As[r][c] = Arow[(size_t)r * D + k0 + c];
            Bs[r][c] = Brow[(size_t)r * D + k0 + c];
        }
        __syncthreads();
        for (int kk = 0; kk < GBK; ++kk) {
            double a[4], b[4];
            for (int u = 0; u < 4; ++u) a[u] = (double)As[tr * 4 + u][kk];
            for (int v = 0; v < 4; ++v) b[v] = (double)Bs[tc * 4 + v][kk];
            for (int u = 0; u < 4; ++u)
                for (int v = 0; v < 4; ++v) acc[u][v] = fma(a[u], b[v], acc[u][v]);
        }
        __syncthreads();
    }
    int rbase = bi * 64 + tr * 4;
    int jbase = bj * 64 + tc * 4;
    for (int u = 0; u < 4; ++u)
        for (int v = 0; v < 4; ++v)
            simT[(size_t)(rbase + u) * N + (jbase + v)] =
                (float)(acc[u][v] * (1.0 / 1024.0));
}

// per-row top-16 in (val desc, idx asc) order over j > i, fp32 comparisons.
__global__ __launch_bounds__(256) void k_topk(const float* __restrict__ simT, int t0,
                                              float* __restrict__ tkv,
                                              int* __restrict__ tki,
                                              int* __restrict__ tkc) {
    int r = blockIdx.x;
    int i = t0 + r;
    int t = threadIdx.x;
    __shared__ float sv[N];
    __shared__ float pv[256];
    __shared__ int pj[256];
    const float* row = simT + (size_t)r * N;
    for (int j = t; j < N; j += 256) {
        float v = NEGF;
        if (j > i) v = row[j];
        sv[j] = v;
    }
    __syncthreads();
    int cnt = 0;
    for (int k = 0; k < TOPK; ++k) {
        float bv = NEGF;
        int bj = 0x7fffffff;
        for (int j = t; j < N; j += 256) {
            float v = sv[j];
            if (v > bv) { bv = v; bj = j; }      // strict > keeps lowest j
        }
        pv[t] = bv; pj[t] = bj;
        __syncthreads();
        for (int s = 128; s > 0; s >>= 1) {
            if (t < s) {
                float ov = pv[t + s]; int oj = pj[t + s];
                if (ov > pv[t] || (ov == pv[t] && oj < pj[t])) { pv[t] = ov; pj[t] = oj; }
            }
            __syncthreads();
        }
        if (pv[0] <= NEGF * 0.5f) break;         // uniform: no candidates left
        if (t == 0) {
            tkv[r * TOPK + k] = pv[0];
            tki[r * TOPK + k] = pj[0];
            sv[pj[0]] = NEGF;
        }
        cnt = k + 1;
        __syncthreads();
    }
    if (t == 0) tkc[r] = cnt;
}

// Sequential greedy matcher, single wave. mg bitset in registers (lane L owns
// cols [64L,64L+64)). Fallback: all 16 row-blocks loaded UNCONDITIONALLY and
// pinned above the compare tree with sched_barrier(0) — one latency wait, not
// 16 serialized remote-L2 round trips. Stale/garbage cols (j <= i, incl. the
// j < t0 region k_gemm skips) are masked to NEGF before ANY comparison.
__global__ __launch_bounds__(64) void k_match(const float* __restrict__ simT,
                                              const float* __restrict__ tkv,
                                              const int* __restrict__ tki,
                                              const int* __restrict__ tkc,
                                              unsigned long long* __restrict__ mgW,
                                              int* __restrict__ partner, int t0,
                                              int* __restrict__ mcnt, int round) {
    __shared__ float ctv[TILE * TOPK];
    __shared__ int cti[TILE * TOPK];
    __shared__ int ccnt[TILE];
    int lane = threadIdx.x;
    for (int x = lane; x < TILE * TOPK; x += 64) { ctv[x] = tkv[x]; cti[x] = tki[x]; }
    for (int x = lane; x < TILE; x += 64) ccnt[x] = tkc[x];
    unsigned long long mw = mgW[lane];           // lane's 64-column mask word
    int nmerge = 0;
    __syncthreads();
    int cnt_n = ccnt[0];
    float v_n = (lane < TOPK) ? ctv[lane] : NEGF;
    int j_n = (lane < TOPK) ? cti[lane] : -1;
    for (int r = 0; r < TILE; ++r) {
        int i = t0 + r;
        int cnt = cnt_n;
        float v = v_n;
        int j = j_n;
        if (r + 1 < TILE) {                      // prefetch next row's candidates
            cnt_n = ccnt[r + 1];
            if (lane < TOPK) {
                v_n = ctv[(r + 1) * TOPK + lane];
                j_n = cti[(r + 1) * TOPK + lane];
            }
        }
        unsigned long long iw = __shfl(mw, i >> 6);
        bool idead = (iw >> (i & 63)) & 1ull;
        if (idead || cnt == 0) {
            if (lane == 0) partner[i] = -1;
            continue;
        }
        unsigned long long jw = __shfl(mw, (j < 0 ? 0 : j) >> 6);
        bool ok = (lane < cnt) && !((jw >> (j & 63)) & 1ull);
        unsigned long long m = __ballot(ok);
        if (m != 0ull) {
            int f = __ffsll((long long)m) - 1;   // first in (val desc, idx asc) order
            float pvv = __shfl(v, f);
            int pjj = __shfl(j, f);
            if (pvv >= THRF) {
                if (lane == (pjj >> 6)) mw |= 1ull << (pjj & 63);
                if (lane == 0) { partner[i] = pjj; ++nmerge; }
            } else if (lane == 0) {
                partner[i] = -1;
            }
        } else {
            float vlast = __shfl(v, TOPK - 1);   // 16th list value, no LDS read
            bool fb = (cnt == TOPK) && (vlast >= THRF) && (N - 1 - i > TOPK);
            if (fb) {
                const float* row = simT + (size_t)r * N;
                // mask words first (VALU-only, no memory)
                unsigned long long wmask[16];
                #pragma unroll
                for (int k = 0; k < 16; ++k)
                    wmask[k] = __shfl(mw, k * 4 + (lane >> 4));
                // ALL 16 independent loads, unconditional, back-to-back
                float4 f4[16];
                #pragma unroll
                for (int k = 0; k < 16; ++k)
                    f4[k] = *(const float4*)(row + k * 256 + 4 * lane);
                __builtin_amdgcn_sched_barrier(0);   // pin loads above compute
                int bbase = (lane & 15) * 4;
                float bv = NEGF;
                int bc = 0x7fffffff;
                #pragma unroll
                for (int k = 0; k < 16; ++k) {
                    unsigned long long w = wmask[k];
                    int cb = k * 256 + 4 * lane;
                    float x0 = (cb + 0 > i && !((w >> (bbase + 0)) & 1ull)) ? f4[k].x : NEGF;
                    float x1 = (cb + 1 > i && !((w >> (bbase + 1)) & 1ull)) ? f4[k].y : NEGF;
                    float x2 = (cb + 2 > i && !((w >> (bbase + 2)) & 1ull)) ? f4[k].z : NEGF;
                    float x3 = (cb + 3 > i && !((w >> (bbase + 3)) & 1ull)) ? f4[k].w : NEGF;
                    float va = (x1 > x0) ? x1 : x0;  int ca = (x1 > x0) ? cb + 1 : cb;
                    float vb = (x3 > x2) ? x3 : x2;  int cd = (x3 > x2) ? cb + 3 : cb + 2;
                    float vk = (vb > va) ? vb : va;  int ck = (vb > va) ? cd : ca;
                    if (vk > bv) { bv = vk; bc = ck; }   // ties keep earlier block
                }
                for (int off = 32; off > 0; off >>= 1) {   // (val desc, col asc)
                    float ov = __shfl_down(bv, off);
                    int oc = __shfl_down(bc, off);
                    if (ov > bv || (ov == bv && oc < bc)) { bv = ov; bc = oc; }
                }
                float bvf = __shfl(bv, 0);
                int bcf = __shfl(bc, 0);
                bool doit = (bcf != 0x7fffffff) && (bvf >= THRF);
                if (doit) {
                    if (lane == (bcf >> 6)) mw |= 1ull << (bcf & 63);
                    if (lane == 0) { partner[i] = bcf; ++nmerge; }
                } else if (lane == 0) {
                    partner[i] = -1;
                }
            } else if (lane == 0) {
                partner[i] = -1;
            }
        }
    }
    mgW[lane] = mw;
    if (lane == 0 && nmerge) atomicAdd(&mcnt[round], nmerge);
}

__global__ void k_apply(const unsigned long long* __restrict__ mgW,
                        uint8_t* __restrict__ alive, uint8_t* __restrict__ consumed) {
    int x = blockIdx.x * blockDim.x + threadIdx.x;
    if (x < N) {
        uint8_t m = (uint8_t)((mgW[x >> 6] >> (x & 63)) & 1ull);
        consumed[x] = m;
        alive[x] = (uint8_t)(alive[x] && !m);
    }
}

__global__ __launch_bounds__(256) void k_count(const uint8_t* __restrict__ alive,
                                               int* __restrict__ acnt, int slot) {
    int x = blockIdx.x * 256 + threadIdx.x;
    int lane = threadIdx.x & 63;
    unsigned long long b = __ballot(alive[x] != 0);
    if (lane == 0) atomicAdd(&acnt[slot], (int)__popcll(b));
}

__global__ void k_fuse(float* __restrict__ E, const int* __restrict__ partner) {
    int i = blockIdx.x;
    int p = partner[i];
    if (p < 0) return;
    float* ri = E + (size_t)i * D;
    const float* rp = E + (size_t)p * D;
    for (int e = threadIdx.x; e < D; e += blockDim.x)
        ri[e] = fminf(ri[e] + rp[e], 1.0f);
}

__global__ void k_zero(float* __restrict__ E, const uint8_t* __restrict__ consumed) {
    int i = blockIdx.x;
    if (!consumed[i]) return;
    float* ri = E + (size_t)i * D;
    for (int e = threadIdx.x; e < D; e += blockDim.x) ri[e] = 0.0f;
}

__global__ void k_alive_out(const uint8_t* __restrict__ alive, float* __restrict__ outA) {
    int x = blockIdx.x * blockDim.x + threadIdx.x;
    if (x < N) outA[x] = alive[x] ? 1.0f : 0.0f;
}

// AUDIT: fires ONLY on invariant violation (after+m==before, 2m<=before).
__global__ void k_diag(const int* __restrict__ mcnt, const int* __restrict__ acnt,
                       float* __restrict__ out) {
    bool bad = false;
    for (int r = 0; r < 4; ++r) {
        int before = acnt[r], after = acnt[r + 1], m = mcnt[r];
        if (after + m != before) bad = true;
        if (2 * m > before) bad = true;
        if (m < 0 || m > 2048) bad = true;
    }
    if (bad) out[0] = (float)(8.0e6 + (double)mcnt[0] * 2048.0 + (double)mcnt[1]);
}

extern "C" void kernel_launch(void* const* d_in, const int* in_sizes, int n_in,
                              void* d_out, int out_size, void* d_ws, size_t ws_size,
                              hipStream_t stream) {
    const float* Ein = (const float*)d_in[0];
    float* E = (float*)d_out;                    // 4096*1024 fp32, updated in place
    float* outAlive = E + (size_t)N * D;         // 4096 floats (0/1)

    // arena = d_in[0] after the on-stream copy below (16 MB guaranteed)
    char* ws = (char*)d_in[0];
    float* simT = (float*)ws;      ws += (size_t)TILE * N * 4;     // 8 MB
    float* tkv = (float*)ws;       ws += (size_t)TILE * TOPK * 4;  // 32 KB
    int* tki = (int*)ws;           ws += (size_t)TILE * TOPK * 4;  // 32 KB
    int* tkc = (int*)ws;           ws += (size_t)TILE * 4;         // 2 KB
    int* partner = (int*)ws;       ws += (size_t)N * 4;            // 16 KB
    int* mcnt = (int*)ws;          ws += 8 * 4;
    int* acnt = (int*)ws;          ws += 8 * 4;
    unsigned long long* mgW = (unsigned long long*)ws; ws += 64 * 8;
    uint8_t* alive = (uint8_t*)ws; ws += N;
    uint8_t* consumed = (uint8_t*)ws;            // total ~8.1 MB << 16 MB

    hipMemcpyAsync(E, Ein, (size_t)N * D * sizeof(float), hipMemcpyDeviceToDevice, stream);
    k_init<<<(N + 255) / 256, 256, 0, stream>>>(alive, mcnt, acnt);

    for (int round = 0; round < 4; ++round) {
        k_mgzero<<<1, 64, 0, stream>>>(mgW);
        for (int tile = 0; tile < N / TILE; ++tile) {
            int t0 = tile * TILE;
            int bx0 = t0 / 64;                    // skip never-read columns j < t0
            k_gemm<<<dim3(64 - bx0, TILE / 64), 256, 0, stream>>>(E, simT, t0, bx0);
            k_topk<<<TILE, 256, 0, stream>>>(simT, t0, tkv, tki, tkc);
            k_match<<<1, 64, 0, stream>>>(simT, tkv, tki, tkc, mgW, partner, t0, mcnt, round);
        }
        k_apply<<<(N + 255) / 256, 256, 0, stream>>>(mgW, alive, consumed);
        k_count<<<16, 256, 0, stream>>>(alive, acnt, round + 1);
        k_fuse<<<N, 256, 0, stream>>>(E, partner);
        k_zero<<<N, 256, 0, stream>>>(E, consumed);
    }
    k_alive_out<<<(N + 255) / 256, 256, 0, stream>>>(alive, outAlive);
    k_diag<<<1, 1, 0, stream>>>(mcnt, acnt, E);   // conditional sentinel only
}